// Round 2
// baseline (327.203 us; speedup 1.0000x reference)
//
#include <hip/hip_runtime.h>
#include <hip/hip_bf16.h>

// LinearAttention collapse (all I/O fp32; x->bf16 only inside the MFMA GEMM):
//   out[b] = x[b] @ W_eff[b] + b_eff[b]
//   W_eff[b] = Wq@Wo + Wk@(diag(aw[b]) * (Wp@Wo))          [256 x 64]
//   b_eff[b] = (bq+bp)@Wo + bo + bk@(diag(aw[b])*(Wp@Wo))  [64]
//   aw[b]    = s_x[b]@Wq + t_sum[b]*bq                     [512]
//   s_x[b]   = sum_n t[b,n]*x[b,n,:],  t_sum[b] = sum_n t[b,n]
//   t[b,n]   = SCALE*(x[b,n].(Wq@qw) + bq.qw)
// Workspace: ~470 KB fp32/bf16 scratch.

#define NN 16384
#define CC 256
#define DD 512
#define HH 64
#define SCALE_F 0.125f

// float-offset workspace layout
#define OFF_SX    0        // [8][256]
#define OFF_TSUM  2048     // [8]
#define OFF_WQQ   2056     // [256]
#define OFF_BQQ   2312     // [1]
#define OFF_WPWO  2320     // [512][64] fp32
#define OFF_WQWO  35088    // [256][64] fp32
#define OFF_CBIAS 51472    // [64]
#define OFF_BEFF  51536    // [8][64]
#define OFF_WEFFT 52048    // bf16 [8][64][256] (byte ofs 208192, 16B aligned)

typedef unsigned short ushort_t;
typedef __attribute__((ext_vector_type(8))) short short8;     // 8 bf16
typedef __attribute__((ext_vector_type(4))) float floatx4;

__device__ __forceinline__ unsigned short f2bf(float f) {
    __hip_bfloat16 h = __float2bfloat16(f);
    return __builtin_bit_cast(unsigned short, h);
}

// ---------------- K0: batch-independent weight folding + zero accumulators ----
__global__ __launch_bounds__(256) void k_prep(
    const float* __restrict__ Wq, const float* __restrict__ bq,
    const float* __restrict__ qw, const float* __restrict__ Wp,
    const float* __restrict__ bp, const float* __restrict__ Wo,
    const float* __restrict__ bo, float* __restrict__ ws)
{
    __shared__ float lds[4096];
    const int tid = threadIdx.x;
    const int bid = blockIdx.x;

    if (bid < 64) {
        // WpWo rows d0..d0+7 : stage 8 rows of Wp in LDS, stream Wo columns
        const int d0 = bid * 8;
        for (int i = tid; i < 4096; i += 256) lds[i] = Wp[d0 * 512 + i];
        __syncthreads();
        for (int o = tid; o < 512; o += 256) {
            const int dl = o >> 6, h = o & 63;
            float acc = 0.f;
            for (int e = 0; e < 512; ++e) acc += lds[dl * 512 + e] * Wo[e * 64 + h];
            ws[OFF_WPWO + (d0 + dl) * 64 + h] = acc;
        }
    } else if (bid == 64) {
        // wqq = Wq @ qw ; bqq = bq . qw ; zero s_x / t_sum
        for (int i = tid; i < 512; i += 256) lds[i] = qw[i];
        __syncthreads();
        {
            const float* wr = Wq + tid * 512;
            float acc = 0.f;
            for (int d = 0; d < 512; ++d) acc += wr[d] * lds[d];
            ws[OFF_WQQ + tid] = acc;
        }
        if (tid == 0) {
            float s = 0.f;
            for (int d = 0; d < 512; ++d) s += bq[d] * lds[d];
            ws[OFF_BQQ] = s;
        }
        for (int i = tid; i < 2056; i += 256) ws[OFF_SX + i] = 0.f;  // s_x + t_sum
    } else if (bid == 65) {
        // cbias[h] = (bq+bp)@Wo + bo
        if (tid < 64) {
            float acc = bo[tid];
            for (int d = 0; d < 512; ++d) acc += (bq[d] + bp[d]) * Wo[d * 64 + tid];
            ws[OFF_CBIAS + tid] = acc;
        }
    } else {
        // WqWo rows c0..c0+7
        const int c0 = (bid - 66) * 8;
        for (int i = tid; i < 4096; i += 256) lds[i] = Wq[c0 * 512 + i];
        __syncthreads();
        for (int o = tid; o < 512; o += 256) {
            const int cl = o >> 6, h = o & 63;
            float acc = 0.f;
            for (int d = 0; d < 512; ++d) acc += lds[cl * 512 + d] * Wo[d * 64 + h];
            ws[OFF_WQWO + (c0 + cl) * 64 + h] = acc;
        }
    }
}

// ---------------- K1: stream x, reduce s_x / t_sum -----------------------
__global__ __launch_bounds__(256) void k_phase1(
    const float* __restrict__ x, float* __restrict__ ws)
{
    const int b = blockIdx.y;
    const int tid = threadIdx.x;
    const int lane = tid & 63;
    const int wave = tid >> 6;

    __shared__ float lacc[256];
    __shared__ float ltsum;
    lacc[tid] = 0.f;
    if (tid == 0) ltsum = 0.f;
    const floatx4 wv = *(const floatx4*)(ws + OFF_WQQ + lane * 4);
    const float bqq = ws[OFF_BQQ];
    __syncthreads();

    const int row0 = blockIdx.x * 128 + wave * 32;
    const float* xb = x + (size_t)b * NN * CC;

    float a0 = 0.f, a1 = 0.f, a2 = 0.f, a3 = 0.f, ts = 0.f;
    for (int i = 0; i < 32; ++i) {
        const floatx4 xv = *(const floatx4*)(xb + (size_t)(row0 + i) * CC + lane * 4);
        float p = xv[0] * wv[0] + xv[1] * wv[1] + xv[2] * wv[2] + xv[3] * wv[3];
        p += __shfl_xor(p, 32);
        p += __shfl_xor(p, 16);
        p += __shfl_xor(p, 8);
        p += __shfl_xor(p, 4);
        p += __shfl_xor(p, 2);
        p += __shfl_xor(p, 1);
        const float t = SCALE_F * (p + bqq);
        a0 += t * xv[0]; a1 += t * xv[1]; a2 += t * xv[2]; a3 += t * xv[3];
        ts += t;
    }
    atomicAdd(&lacc[lane * 4 + 0], a0);
    atomicAdd(&lacc[lane * 4 + 1], a1);
    atomicAdd(&lacc[lane * 4 + 2], a2);
    atomicAdd(&lacc[lane * 4 + 3], a3);
    if (lane == 0) atomicAdd(&ltsum, ts);
    __syncthreads();
    atomicAdd(&ws[OFF_SX + b * 256 + tid], lacc[tid]);
    if (tid == 0) atomicAdd(&ws[OFF_TSUM + b], ltsum);
}

// ---------------- K2: aw -> W_effT (bf16) + b_eff -------------------------
__global__ __launch_bounds__(256) void k_weff(
    const float* __restrict__ Wq, const float* __restrict__ bq,
    const float* __restrict__ Wk, const float* __restrict__ bk,
    float* __restrict__ ws)
{
    const int b = blockIdx.y;
    const int c0 = blockIdx.x * 32;
    const int tid = threadIdx.x;

    __shared__ float lsx[256];
    __shared__ float law[512];
    __shared__ float lts;
    __shared__ float wpT[128 * 64];   // 32 KB tile of WpWo
    lsx[tid] = ws[OFF_SX + b * 256 + tid];
    if (tid == 0) lts = ws[OFF_TSUM + b];
    __syncthreads();
    const float tsum = lts;

    // aw[d] = s_x @ Wq[:,d] + tsum*bq[d]   (coalesced over d)
    for (int d = tid; d < 512; d += 256) {
        float acc = tsum * bq[d];
        for (int c = 0; c < 256; ++c) acc += lsx[c] * Wq[c * 512 + d];
        law[d] = acc;
    }
    __syncthreads();

    // W_eff[c,h] = WqWo[c,h] + sum_d Wk[c,d]*aw[d]*WpWo[d,h]
    const int c = c0 + (tid >> 3);
    const int hb = (tid & 7) * 8;
    float acc[8];
#pragma unroll
    for (int j = 0; j < 8; ++j) acc[j] = ws[OFF_WQWO + c * 64 + hb + j];

    for (int t4 = 0; t4 < 4; ++t4) {
        const int d0 = t4 * 128;
        for (int i = tid; i < 8192; i += 256) wpT[i] = ws[OFF_WPWO + d0 * 64 + i];
        __syncthreads();
        for (int dl = 0; dl < 128; ++dl) {
            const float g = Wk[c * 512 + d0 + dl] * law[d0 + dl];
            const floatx4 p0 = *(const floatx4*)(wpT + dl * 64 + hb);
            const floatx4 p1 = *(const floatx4*)(wpT + dl * 64 + hb + 4);
            acc[0] += g * p0[0]; acc[1] += g * p0[1];
            acc[2] += g * p0[2]; acc[3] += g * p0[3];
            acc[4] += g * p1[0]; acc[5] += g * p1[1];
            acc[6] += g * p1[2]; acc[7] += g * p1[3];
        }
        __syncthreads();
    }

    ushort_t* wt = (ushort_t*)(ws + OFF_WEFFT) + (size_t)b * (HH * CC);
#pragma unroll
    for (int j = 0; j < 8; ++j)
        wt[(size_t)(hb + j) * CC + c] = f2bf(acc[j]);

    // b_eff (once per batch); law persists in LDS
    if (blockIdx.x == 0 && tid < 64) {
        float a = ws[OFF_CBIAS + tid];
        for (int d = 0; d < 512; ++d)
            a += bk[d] * law[d] * ws[OFF_WPWO + d * 64 + tid];
        ws[OFF_BEFF + b * 64 + tid] = a;
    }
}

// ---------------- K3: out = x @ W_eff + b_eff  (MFMA bf16) -----------------
__global__ __launch_bounds__(256) void k_out(
    const float* __restrict__ x, const float* __restrict__ ws,
    float* __restrict__ out)
{
    const int b = blockIdx.y;
    const int tid = threadIdx.x;
    const int lane = tid & 63;
    const int wave = tid >> 6;
    const int quad = lane >> 4;
    const int l15 = lane & 15;
    const int row0 = blockIdx.x * 64 + wave * 16;

    // Stage W_effT[b] in LDS, stride 264 (pad 8) -> 2-way-free ds_read_b128
    __shared__ __align__(16) ushort_t lwt[64 * 264];
    const ushort_t* wt = (const ushort_t*)(ws + OFF_WEFFT) + (size_t)b * (HH * CC);
    for (int o = tid; o < 2048; o += 256) {
        const int h = o >> 5, seg = o & 31;
        *(short8*)(lwt + h * 264 + seg * 8) = *(const short8*)(wt + h * 256 + seg * 8);
    }

    // A fragments: A[m=l15][k = kk*32 + quad*8 + j], fp32 -> bf16
    const float* xr = x + ((size_t)b * NN + row0 + l15) * CC + quad * 8;
    short8 afrag[8];
#pragma unroll
    for (int kk = 0; kk < 8; ++kk) {
        const floatx4 u0 = *(const floatx4*)(xr + kk * 32);
        const floatx4 u1 = *(const floatx4*)(xr + kk * 32 + 4);
        short8 t;
        t[0] = (short)f2bf(u0[0]); t[1] = (short)f2bf(u0[1]);
        t[2] = (short)f2bf(u0[2]); t[3] = (short)f2bf(u0[3]);
        t[4] = (short)f2bf(u1[0]); t[5] = (short)f2bf(u1[1]);
        t[6] = (short)f2bf(u1[2]); t[7] = (short)f2bf(u1[3]);
        afrag[kk] = t;
    }
    __syncthreads();

    floatx4 acc[4];
#pragma unroll
    for (int ht = 0; ht < 4; ++ht)
#pragma unroll
        for (int r = 0; r < 4; ++r) acc[ht][r] = 0.f;

#pragma unroll
    for (int kk = 0; kk < 8; ++kk)
#pragma unroll
        for (int ht = 0; ht < 4; ++ht) {
            const short8 bf =
                *(const short8*)(lwt + (ht * 16 + l15) * 264 + quad * 8 + kk * 32);
            acc[ht] = __builtin_amdgcn_mfma_f32_16x16x32_bf16(
                afrag[kk], bf, acc[ht], 0, 0, 0);
        }

    // D: col = lane&15 (h within tile), row = quad*4 + reg
    const float* beff = ws + OFF_BEFF + b * 64;
#pragma unroll
    for (int ht = 0; ht < 4; ++ht) {
        const int h = ht * 16 + l15;
        const float bias = beff[h];
#pragma unroll
        for (int r = 0; r < 4; ++r) {
            const int row = row0 + quad * 4 + r;
            out[((size_t)b * NN + row) * HH + h] = acc[ht][r] + bias;
        }
    }
}

extern "C" void kernel_launch(void* const* d_in, const int* in_sizes, int n_in,
                              void* d_out, int out_size, void* d_ws, size_t ws_size,
                              hipStream_t stream) {
    const float* x  = (const float*)d_in[0];
    const float* Wq = (const float*)d_in[1];
    const float* bq = (const float*)d_in[2];
    const float* Wk = (const float*)d_in[3];
    const float* bk = (const float*)d_in[4];
    const float* qw = (const float*)d_in[5];
    const float* Wp = (const float*)d_in[6];
    const float* bp = (const float*)d_in[7];
    const float* Wo = (const float*)d_in[8];
    const float* bo = (const float*)d_in[9];
    float* ws = (float*)d_ws;
    float* out = (float*)d_out;

    hipLaunchKernelGGL(k_prep,   dim3(98),      dim3(256), 0, stream,
                       Wq, bq, qw, Wp, bp, Wo, bo, ws);
    hipLaunchKernelGGL(k_phase1, dim3(128, 8),  dim3(256), 0, stream, x, ws);
    hipLaunchKernelGGL(k_weff,   dim3(8, 8),    dim3(256), 0, stream,
                       Wq, bq, Wk, bk, ws);
    hipLaunchKernelGGL(k_out,    dim3(256, 8),  dim3(256), 0, stream, x, ws, out);
}